// Round 1
// baseline (146.825 us; speedup 1.0000x reference)
//
#include <hip/hip_runtime.h>
#include <hip/hip_bf16.h>

// n=8192 rows, d=256 feat, 10 classes.
// loss = mean_i log1p(exp(0.5/0.7) * A_i * B_i)
//   A_i = sum_{j: y_j!=y_i} exp(sim_ij/0.7), B_i = sum_{j!=i: y_j==y_i} exp(-sim_ij/0.7)
//   sim = rownorm(P) @ rownorm(P)^T
//
// R8: exploit symmetry of sim. Block (I,C) = rows panel I (128) x col group C
// (256 cols, 4 chunks of 64), exists iff I < 2C+2 -> grid = NG*(NG+1) = 1056.
// Each element (i,j): row-accumulate into A/B[i] always; col-accumulate the SAME
// exp value into A/B[j] iff (j>>8) > (i>>8), i.e. block-uniform colacc = (C > I>>1)
// -- covers every ordered pair exactly once (cross tiles inside each 256-group
// diagonal computed both ways, ~3% redundancy). Halves MFMA, LDS reads, exps.
// Column partials: quad-reduce (shfl 16/32) -> LDS atomic -> one flush per block.
// Structure otherwise = proven R7: kc-major B via global_load_lds DMA (conflict-
// free), single buffer, 2 barriers/chunk, DMA(c+1) issued before epilogue(c).

#define NF 256
#define TINV (1.0f / 0.7f)
#define SC2 2.0609929398439434f  // (1/0.7)*log2(e)

typedef __attribute__((ext_vector_type(8))) short short8;
typedef __attribute__((ext_vector_type(4))) float float4v;

typedef const __attribute__((address_space(1))) unsigned int glb_u32;
typedef __attribute__((address_space(3))) unsigned int lds_u32;

// One wave per row: normalize to bf16. Also zeroes the accumulators.
__global__ __launch_bounds__(256)
void k_prep(const float* __restrict__ P, unsigned short* __restrict__ Pn,
            float* __restrict__ AB) {  // AB = Aacc||Bacc, 2n floats
    int wave = threadIdx.x >> 6, lane = threadIdx.x & 63;
    int row = blockIdx.x * 4 + wave;
    if (threadIdx.x < 8) AB[blockIdx.x * 8 + threadIdx.x] = 0.f;
    float4 v = *(const float4*)(P + (size_t)row * NF + lane * 4);
    float sq = v.x * v.x + v.y * v.y + v.z * v.z + v.w * v.w;
#pragma unroll
    for (int off = 32; off; off >>= 1) sq += __shfl_xor(sq, off, 64);
    float r = rsqrtf(sq);
    __hip_bfloat16 h0 = __float2bfloat16(v.x * r), h1 = __float2bfloat16(v.y * r),
                   h2 = __float2bfloat16(v.z * r), h3 = __float2bfloat16(v.w * r);
    ushort4 o = { *(unsigned short*)&h0, *(unsigned short*)&h1,
                  *(unsigned short*)&h2, *(unsigned short*)&h3 };
    *(ushort4*)(Pn + (size_t)row * NF + lane * 4) = o;
}

__global__ __launch_bounds__(256, 3)
void k_main(const unsigned short* __restrict__ Pn, const int* __restrict__ y,
            float* __restrict__ Aacc, float* __restrict__ Bacc) {
    // B chunk: 64 cols x K=256, kc-major: ushort addr = kc*512 + col*8
    __shared__ __align__(16) unsigned short Bs[64 * NF];
    __shared__ int yc[256];
    __shared__ float colA[256], colB[256];

    const int tid = threadIdx.x;
    // Decode (I, C): cumulative blocks before group C is C*(C+1).
    int bid = blockIdx.x;
    int C = (int)((sqrtf(4.0f * (float)bid + 1.0f) - 1.0f) * 0.5f);
    while (C * (C + 1) > bid) --C;
    while ((C + 1) * (C + 2) <= bid) ++C;
    const int I = bid - C * (C + 1);          // row panel, I in [0, 2C+2)
    const int rb = I * 128, cb0 = C * 256;
    const bool colacc = (C > (I >> 1));       // uniform: col panels strictly above row panel

    const int lane = tid & 63, wave = tid >> 6;
    const int quad = lane >> 4, l15 = lane & 15;

    // DMA one 64-col chunk: 32 instrs (8 per wave), lane L -> col L.
    // kc-instr: lane L reads Pn[(cb0+c*64+L)*NF + kc*8], lands at kc*1024+L*16 B.
#define DMA_CHUNK(c)                                                          \
    {                                                                         \
        _Pragma("unroll")                                                     \
        for (int i = 0; i < 8; ++i) {                                         \
            const int kc = wave * 8 + i;                                      \
            const unsigned short* src =                                       \
                Pn + (size_t)(cb0 + (c) * 64 + lane) * NF + kc * 8;           \
            __builtin_amdgcn_global_load_lds((glb_u32*)src,                   \
                (lds_u32*)&Bs[kc * 512], 16, 0, 0);                           \
        }                                                                     \
    }

    DMA_CHUNK(0)   // issue first so DMA latency overlaps A-frag loads

    yc[tid] = y[cb0 + tid];
    colA[tid] = 0.f;
    colB[tid] = 0.f;

    // A-frags: this wave's 32 rows x full K. m=l15, k=quad*8+j (16x16x32).
    const unsigned short* pa = Pn + (size_t)(rb + wave * 32 + l15) * NF + quad * 8;
    short8 afr[2][8];
#pragma unroll
    for (int tr = 0; tr < 2; ++tr)
#pragma unroll
        for (int ks = 0; ks < 8; ++ks)
            afr[tr][ks] = *(const short8*)(pa + (size_t)tr * 16 * NF + ks * 32);

    // Row classes byte-packed (rows tr*16 + quad*4 + r).
    unsigned yis[2];
#pragma unroll
    for (int tr = 0; tr < 2; ++tr) {
        int4 v = *(const int4*)(y + rb + wave * 32 + tr * 16 + quad * 4);
        yis[tr] = (unsigned)(v.x & 255) | ((unsigned)(v.y & 255) << 8) |
                  ((unsigned)(v.z & 255) << 16) | ((unsigned)(v.w & 255) << 24);
    }

    float rA[2][4], rB[2][4];
#pragma unroll
    for (int tr = 0; tr < 2; ++tr)
#pragma unroll
        for (int r = 0; r < 4; ++r) { rA[tr][r] = 0.f; rB[tr][r] = 0.f; }

#pragma unroll 1
    for (int c = 0; c < 4; ++c) {
        __syncthreads();   // own-vmcnt drained by compiler before barrier -> Bs ready

        float4v acc[2][4];
#pragma unroll
        for (int a = 0; a < 2; ++a)
#pragma unroll
            for (int b = 0; b < 4; ++b) acc[a][b] = (float4v){0.f, 0.f, 0.f, 0.f};

#pragma unroll
        for (int ks = 0; ks < 8; ++ks) {
            short8 fb[4];
#pragma unroll
            for (int tc = 0; tc < 4; ++tc)
                fb[tc] = *(const short8*)&Bs[(ks * 4 + quad) * 512 + (tc * 16 + l15) * 8];
#pragma unroll
            for (int tr = 0; tr < 2; ++tr)
#pragma unroll
                for (int tc = 0; tc < 4; ++tc)
                    acc[tr][tc] = __builtin_amdgcn_mfma_f32_16x16x32_bf16(
                        afr[tr][ks], fb[tc], acc[tr][tc], 0, 0, 0);
        }
        __syncthreads();   // all waves done reading Bs
        if (c < 3) DMA_CHUNK(c + 1)

        // Fused epilogue. C/D: col=l15, row=quad*4+reg.
#pragma unroll
        for (int tc = 0; tc < 4; ++tc) {
            const int jl = c * 64 + tc * 16 + l15;
            const int yj = yc[jl];
            const int gj = cb0 + jl;
            float ca = 0.f, cbv = 0.f;   // column partials (sum over this wave's 32 rows)
#pragma unroll
            for (int tr = 0; tr < 2; ++tr) {
                const int gi0 = rb + wave * 32 + tr * 16 + quad * 4;
#pragma unroll
                for (int r = 0; r < 4; ++r) {
                    const float s = acc[tr][tc][r];
                    const int cls = (yis[tr] >> (8 * r)) & 255;
                    const bool same = (cls == yj);
                    const float e = exp2f(s * (same ? -SC2 : SC2));
                    rA[tr][r] += same ? 0.f : e;
                    rB[tr][r] += (same && (gi0 + r != gj)) ? e : 0.f;
                    ca  += same ? 0.f : e;   // col-side: gi != gj guaranteed when flushed
                    cbv += same ? e : 0.f;
                }
            }
            if (colacc) {   // uniform branch
                ca  += __shfl_xor(ca, 16, 64);  ca  += __shfl_xor(ca, 32, 64);
                cbv += __shfl_xor(cbv, 16, 64); cbv += __shfl_xor(cbv, 32, 64);
                if (quad == 0) {
                    atomicAdd(&colA[jl], ca);
                    atomicAdd(&colB[jl], cbv);
                }
            }
        }
    }

    // Row side: butterfly over 16 col-lanes; quad leaders issue atomics.
#pragma unroll
    for (int tr = 0; tr < 2; ++tr)
#pragma unroll
        for (int r = 0; r < 4; ++r) {
#pragma unroll
            for (int off = 1; off < 16; off <<= 1) {
                rA[tr][r] += __shfl_xor(rA[tr][r], off, 64);
                rB[tr][r] += __shfl_xor(rB[tr][r], off, 64);
            }
        }
    if (l15 == 0) {
#pragma unroll
        for (int tr = 0; tr < 2; ++tr)
#pragma unroll
            for (int r = 0; r < 4; ++r) {
                const int gi = rb + wave * 32 + tr * 16 + quad * 4 + r;
                atomicAdd(&Aacc[gi], rA[tr][r]);
                atomicAdd(&Bacc[gi], rB[tr][r]);
            }
    }

    // Column side: flush block-local LDS accumulators once.
    if (colacc) {
        __syncthreads();   // all waves' chunk-3 LDS atomics done (uniform branch)
        atomicAdd(&Aacc[cb0 + tid], colA[tid]);
        atomicAdd(&Bacc[cb0 + tid], colB[tid]);
    }
}

// Single block: ballot-based class histogram, mean loss, direct write of out[0].
__global__ __launch_bounds__(1024)
void k_final(const float* __restrict__ Aacc, const float* __restrict__ Bacc,
             const int* __restrict__ y, float* __restrict__ out, int n) {
    __shared__ int hist[16];
    __shared__ float red[16];
    const int tid = threadIdx.x;
    if (tid < 16) hist[tid] = 0;
    __syncthreads();
    int loc[10];
#pragma unroll
    for (int cc = 0; cc < 10; ++cc) loc[cc] = 0;
    for (int i = tid; i < n; i += 1024) {
        const int yv = y[i];
#pragma unroll
        for (int cc = 0; cc < 10; ++cc) {
            unsigned long long m = __ballot(yv == cc);
            if ((tid & 63) == 0) loc[cc] += __popcll(m);
        }
    }
    if ((tid & 63) == 0)
#pragma unroll
        for (int cc = 0; cc < 10; ++cc) atomicAdd(&hist[cc], loc[cc]);
    __syncthreads();
    const float M = __expf(0.5f * TINV);
    float s = 0.f;
    for (int i = tid; i < n; i += 1024) {
        const int cc = hist[y[i] & 15];
        const float a = (n - cc) > 0 ? Aacc[i] : 1.0f;
        const float b = (cc - 1) > 0 ? Bacc[i] : 1.0f;
        s += log1pf(M * a * b);
    }
#pragma unroll
    for (int off = 32; off; off >>= 1) s += __shfl_xor(s, off, 64);
    if ((tid & 63) == 0) red[tid >> 6] = s;
    __syncthreads();
    if (tid == 0) {
        float t = 0.f;
#pragma unroll
        for (int w = 0; w < 16; ++w) t += red[w];
        out[0] = t / (float)n;
    }
}

extern "C" void kernel_launch(void* const* d_in, const int* in_sizes, int n_in,
                              void* d_out, int out_size, void* d_ws, size_t ws_size,
                              hipStream_t stream) {
    const float* P = (const float*)d_in[0];
    const int* y   = (const int*)d_in[1];
    float* out     = (float*)d_out;
    const int n = in_sizes[1];  // 8192

    // ws: Pn bf16 [n*256] | Aacc f32 [n] | Bacc f32 [n]
    unsigned short* Pn = (unsigned short*)d_ws;
    float* Aacc = (float*)((char*)d_ws + (size_t)n * NF * 2);
    float* Bacc = Aacc + n;

    const int ng = n / 256;  // col groups of 256
    k_prep<<<n / 4, 256, 0, stream>>>(P, Pn, Aacc);
    k_main<<<ng * (ng + 1), 256, 0, stream>>>(Pn, y, Aacc, Bacc);
    k_final<<<1, 1024, 0, stream>>>(Aacc, Bacc, y, out, n);
}